// Round 2
// baseline (529.589 us; speedup 1.0000x reference)
//
#include <hip/hip_runtime.h>
#include <hip/hip_bf16.h>
#include <cstdint>

#define B_  4
#define LQ_ 2048
#define LK_ 2048
#define D_  1024
#define H_  16
#define HD_ 64

typedef __attribute__((ext_vector_type(8))) short bf16x8;   // 8 bf16 in 4 VGPRs
typedef __attribute__((ext_vector_type(4))) float f32x4;    // MFMA C/D

__device__ __forceinline__ float b2f(unsigned short s) {
    union { unsigned u; float f; } v; v.u = ((unsigned)s) << 16; return v.f;
}
__device__ __forceinline__ unsigned short f2b(float f) {
    union { float f; unsigned u; } v; v.f = f;
    unsigned u = v.u;
    unsigned r = (u + 0x7fffu + ((u >> 16) & 1u)) >> 16;  // RNE
    return (unsigned short)r;
}

// ---------------------------------------------------------------------------
// Projection GEMM: Y[m][n] = sum_k X[m][k] * W[n][k] + bias[n]
// X, W, bias are fp32; converted to bf16 during LDS staging; Y is bf16.
// M=8192, N=1024, K=1024. Block=256 thr (4 waves), tile 128x128, BK=32.
// ---------------------------------------------------------------------------
__global__ __launch_bounds__(256) void proj_gemm(
    const float* __restrict__ X,
    const float* __restrict__ W,
    const float* __restrict__ bias,
    unsigned short* __restrict__ Y)
{
    const int K = 1024;
    __shared__ unsigned short As[128 * 40];   // [row][k] pad 32->40
    __shared__ unsigned short Bs[128 * 40];

    const int tid  = threadIdx.x;
    const int lane = tid & 63;
    const int w    = tid >> 6;
    const int wm   = w & 1, wn = w >> 1;
    const int m0   = blockIdx.y * 128;
    const int n0   = blockIdx.x * 128;
    const int l15  = lane & 15, quad = lane >> 4;

    f32x4 acc[4][4] = {};

    const int srow = tid >> 2;   // 0..63
    const int skg  = tid & 3;    // 0..3  (8 floats each)

    for (int k0 = 0; k0 < K; k0 += 32) {
        __syncthreads();
        #pragma unroll
        for (int it = 0; it < 2; ++it) {
            int row = srow + it * 64;
            const float* gA = X + (size_t)(m0 + row) * K + k0 + skg * 8;
            float4 a0 = *(const float4*)gA;
            float4 a1 = *(const float4*)(gA + 4);
            bf16x8 av;
            av[0] = (short)f2b(a0.x); av[1] = (short)f2b(a0.y);
            av[2] = (short)f2b(a0.z); av[3] = (short)f2b(a0.w);
            av[4] = (short)f2b(a1.x); av[5] = (short)f2b(a1.y);
            av[6] = (short)f2b(a1.z); av[7] = (short)f2b(a1.w);
            *(bf16x8*)(&As[row * 40 + skg * 8]) = av;

            const float* gB = W + (size_t)(n0 + row) * K + k0 + skg * 8;
            float4 b0 = *(const float4*)gB;
            float4 b1 = *(const float4*)(gB + 4);
            bf16x8 bvv;
            bvv[0] = (short)f2b(b0.x); bvv[1] = (short)f2b(b0.y);
            bvv[2] = (short)f2b(b0.z); bvv[3] = (short)f2b(b0.w);
            bvv[4] = (short)f2b(b1.x); bvv[5] = (short)f2b(b1.y);
            bvv[6] = (short)f2b(b1.z); bvv[7] = (short)f2b(b1.w);
            *(bf16x8*)(&Bs[row * 40 + skg * 8]) = bvv;
        }
        __syncthreads();

        bf16x8 af[4], bf[4];
        #pragma unroll
        for (int mt = 0; mt < 4; ++mt)
            af[mt] = *(const bf16x8*)(&As[(wm * 64 + mt * 16 + l15) * 40 + quad * 8]);
        #pragma unroll
        for (int nt = 0; nt < 4; ++nt)
            bf[nt] = *(const bf16x8*)(&Bs[(wn * 64 + nt * 16 + l15) * 40 + quad * 8]);

        #pragma unroll
        for (int mt = 0; mt < 4; ++mt)
            #pragma unroll
            for (int nt = 0; nt < 4; ++nt)
                acc[mt][nt] = __builtin_amdgcn_mfma_f32_16x16x32_bf16(
                    af[mt], bf[nt], acc[mt][nt], 0, 0, 0);
    }

    float bv[4];
    #pragma unroll
    for (int nt = 0; nt < 4; ++nt)
        bv[nt] = bias[n0 + wn * 64 + nt * 16 + l15];

    #pragma unroll
    for (int mt = 0; mt < 4; ++mt) {
        #pragma unroll
        for (int r = 0; r < 4; ++r) {
            int row = m0 + wm * 64 + mt * 16 + quad * 4 + r;   // C/D: row = quad*4+reg
            unsigned short* yp = Y + (size_t)row * 1024 + n0 + wn * 64;
            #pragma unroll
            for (int nt = 0; nt < 4; ++nt)
                yp[nt * 16 + l15] = f2b(acc[mt][nt][r] + bv[nt]);   // col = lane&15
        }
    }
}

// ---------------------------------------------------------------------------
// Flash attention. Grid: (qtile=32, head=16, batch=4). Block=256 (4 waves),
// 64 queries/block (16/wave), K-tiles of 32 keys. Q/K/V are bf16 (ws),
// output fp32. Computes S^T = K * Q^T so softmax reduce is cross-quad shfl.
// ---------------------------------------------------------------------------
__global__ __launch_bounds__(256) void attn_kernel(
    const unsigned short* __restrict__ Q,
    const unsigned short* __restrict__ Kp,
    const unsigned short* __restrict__ Vp,
    float* __restrict__ Out)
{
    __shared__ unsigned short Ks[32 * 72];     // [key][d], pad 64->72
    __shared__ unsigned short Vt[64 * 40];     // [d][key], pad 32->40
    __shared__ unsigned short Ps[4][16 * 40];  // per-wave P [query][key], pad 32->40

    const int tid  = threadIdx.x;
    const int lane = tid & 63;
    const int w    = tid >> 6;
    const int l15  = lane & 15, quad = lane >> 4;
    const int b = blockIdx.z, h = blockIdx.y, qt = blockIdx.x;

    // preload Q fragment: query row = l15 of wave tile; contiguous d
    const unsigned short* qptr =
        Q + ((size_t)(b * LQ_ + qt * 64 + w * 16 + l15)) * 1024 + h * 64;
    bf16x8 qf[2];
    qf[0] = *(const bf16x8*)(qptr + 0  + quad * 8);
    qf[1] = *(const bf16x8*)(qptr + 32 + quad * 8);

    float mrow = -1e30f, lrow = 0.0f;   // state for query l15 (replicated x4 quads)
    f32x4 oacc[4] = {};

    const int skey = tid >> 3;   // 0..31
    const int sdg  = tid & 7;    // 0..7
    const float scale = 0.125f;  // 1/sqrt(64)

    for (int k0 = 0; k0 < LK_; k0 += 32) {
        __syncthreads();
        {   // stage K tile [32][64] and V tile transposed [64][32]
            const size_t grow = (size_t)(b * LK_ + k0 + skey) * 1024 + h * 64 + sdg * 8;
            *(bf16x8*)(&Ks[skey * 72 + sdg * 8]) = *(const bf16x8*)(Kp + grow);
            bf16x8 vv = *(const bf16x8*)(Vp + grow);
            #pragma unroll
            for (int j = 0; j < 8; ++j)
                Vt[(sdg * 8 + j) * 40 + skey] = (unsigned short)vv[j];
        }
        __syncthreads();

        // S^T tiles: A=K rows (m=key=l15), B=Q (n=query=l15); C: col=query, row=key
        f32x4 st[2];
        #pragma unroll
        for (int t = 0; t < 2; ++t) {
            f32x4 s = {};
            #pragma unroll
            for (int dblk = 0; dblk < 2; ++dblk) {
                bf16x8 kf = *(const bf16x8*)(&Ks[(t * 16 + l15) * 72 + dblk * 32 + quad * 8]);
                s = __builtin_amdgcn_mfma_f32_16x16x32_bf16(kf, qf[dblk], s, 0, 0, 0);
            }
            st[t] = s;
        }

        // online softmax over 32 keys (this lane holds keys {t*16+quad*4+r} for query l15)
        float pm = -1e30f;
        #pragma unroll
        for (int t = 0; t < 2; ++t)
            #pragma unroll
            for (int r = 0; r < 4; ++r) {
                float v = st[t][r] * scale;
                st[t][r] = v;
                pm = fmaxf(pm, v);
            }
        pm = fmaxf(pm, __shfl_xor(pm, 16, 64));
        pm = fmaxf(pm, __shfl_xor(pm, 32, 64));
        float mnew  = fmaxf(mrow, pm);
        float alpha = __expf(mrow - mnew);
        float psum  = 0.0f;
        #pragma unroll
        for (int t = 0; t < 2; ++t)
            #pragma unroll
            for (int r = 0; r < 4; ++r) {
                float p = __expf(st[t][r] - mnew);
                st[t][r] = p;
                psum += p;
            }
        psum += __shfl_xor(psum, 16, 64);
        psum += __shfl_xor(psum, 32, 64);
        lrow = lrow * alpha + psum;
        mrow = mnew;

        // P -> LDS [query][key] (bf16), then read back in A-layout
        unsigned short* pbase = &Ps[w][0];
        #pragma unroll
        for (int t = 0; t < 2; ++t) {
            ushort4 pk;
            pk.x = f2b(st[t][0]); pk.y = f2b(st[t][1]);
            pk.z = f2b(st[t][2]); pk.w = f2b(st[t][3]);
            *(ushort4*)(&pbase[l15 * 40 + t * 16 + quad * 4]) = pk;
        }
        __syncthreads();   // conservative: orders P write -> P read, Vt reuse

        bf16x8 pf = *(const bf16x8*)(&pbase[l15 * 40 + quad * 8]);  // A[m=query][k=key]

        float al[4];
        #pragma unroll
        for (int r = 0; r < 4; ++r) al[r] = __shfl(alpha, quad * 4 + r, 64);

        #pragma unroll
        for (int nt = 0; nt < 4; ++nt) {
            bf16x8 vf = *(const bf16x8*)(&Vt[(nt * 16 + l15) * 40 + quad * 8]); // B[k=key][n=dim]
            f32x4 o = oacc[nt];
            #pragma unroll
            for (int r = 0; r < 4; ++r) o[r] *= al[r];
            o = __builtin_amdgcn_mfma_f32_16x16x32_bf16(pf, vf, o, 0, 0, 0);
            oacc[nt] = o;
        }
    }

    // epilogue: rows of oacc are queries quad*4+r; fetch 1/l via shuffle
    float invl = 1.0f / lrow;
    float il[4];
    #pragma unroll
    for (int r = 0; r < 4; ++r) il[r] = __shfl(invl, quad * 4 + r, 64);

    #pragma unroll
    for (int nt = 0; nt < 4; ++nt) {
        #pragma unroll
        for (int r = 0; r < 4; ++r) {
            size_t orow = (size_t)(b * LQ_ + qt * 64 + w * 16 + quad * 4 + r);
            Out[orow * 1024 + h * 64 + nt * 16 + l15] = oacc[nt][r] * il[r];
        }
    }
}

// ---------------------------------------------------------------------------
extern "C" void kernel_launch(void* const* d_in, const int* in_sizes, int n_in,
                              void* d_out, int out_size, void* d_ws, size_t ws_size,
                              hipStream_t stream) {
    const float* zt = (const float*)d_in[0];
    const float* ic = (const float*)d_in[1];
    const float* Wq = (const float*)d_in[2];
    const float* bq = (const float*)d_in[3];
    const float* Wk = (const float*)d_in[4];
    const float* bk = (const float*)d_in[5];
    const float* Wv = (const float*)d_in[6];
    const float* bv = (const float*)d_in[7];
    float* out = (float*)d_out;

    unsigned short* Qb = (unsigned short*)d_ws;
    unsigned short* Kb = Qb + (size_t)8192 * 1024;
    unsigned short* Vb = Kb + (size_t)8192 * 1024;

    dim3 gproj(8, 64);                       // N/128, M/128
    proj_gemm<<<gproj, 256, 0, stream>>>(zt, Wq, bq, Qb);
    proj_gemm<<<gproj, 256, 0, stream>>>(ic, Wk, bk, Kb);
    proj_gemm<<<gproj, 256, 0, stream>>>(ic, Wv, bv, Vb);

    dim3 gattn(32, 16, 4);                   // LQ/64, H, B
    attn_kernel<<<gattn, 256, 0, stream>>>(Qb, Kb, Vb, out);
}

// Round 3
// 385.919 us; speedup vs baseline: 1.3723x; 1.3723x over previous
//
#include <hip/hip_runtime.h>
#include <hip/hip_bf16.h>
#include <cstdint>

#define B_  4
#define LQ_ 2048
#define LK_ 2048
#define D_  1024
#define H_  16
#define HD_ 64

typedef __attribute__((ext_vector_type(8))) short bf16x8;   // 8 bf16 in 4 VGPRs
typedef __attribute__((ext_vector_type(4))) float f32x4;    // MFMA C/D

__device__ __forceinline__ unsigned short f2b(float f) {
    union { float f; unsigned u; } v; v.f = f;
    unsigned u = v.u;
    unsigned r = (u + 0x7fffu + ((u >> 16) & 1u)) >> 16;  // RNE
    return (unsigned short)r;
}

// ---------------------------------------------------------------------------
// fp32 -> bf16 conversion (optionally scaled). 8 elems/thread, grid-stride.
// ---------------------------------------------------------------------------
__global__ void cvt_bf16(const float* __restrict__ in,
                         unsigned short* __restrict__ out, int n, float scale) {
    int i = (blockIdx.x * blockDim.x + threadIdx.x) * 8;
    int stride = gridDim.x * blockDim.x * 8;
    for (; i < n; i += stride) {
        float4 a = *(const float4*)(in + i);
        float4 b = *(const float4*)(in + i + 4);
        bf16x8 v;
        v[0] = (short)f2b(a.x * scale); v[1] = (short)f2b(a.y * scale);
        v[2] = (short)f2b(a.z * scale); v[3] = (short)f2b(a.w * scale);
        v[4] = (short)f2b(b.x * scale); v[5] = (short)f2b(b.y * scale);
        v[6] = (short)f2b(b.z * scale); v[7] = (short)f2b(b.w * scale);
        *(bf16x8*)(out + i) = v;
    }
}

// ---------------------------------------------------------------------------
// Projection GEMM (bf16 in, bf16 out): Y[m][n] = sum_k X[m][k]*W[n][k] + bs*bias[n]
// M=8192, N=1024, K=1024. Block=256 (4 waves), tile 128x128, BK=32.
// ---------------------------------------------------------------------------
__global__ __launch_bounds__(256) void proj_gemm(
    const unsigned short* __restrict__ X,
    const unsigned short* __restrict__ W,
    const float* __restrict__ bias, float bscale,
    unsigned short* __restrict__ Y)
{
    const int K = 1024;
    __shared__ unsigned short As[128 * 40];   // [row][k] pad 32->40
    __shared__ unsigned short Bs[128 * 40];

    const int tid  = threadIdx.x;
    const int lane = tid & 63;
    const int w    = tid >> 6;
    const int wm   = w & 1, wn = w >> 1;
    const int m0   = blockIdx.y * 128;
    const int n0   = blockIdx.x * 128;
    const int l15  = lane & 15, quad = lane >> 4;

    f32x4 acc[4][4] = {};

    const int srow = tid >> 2;   // 0..63
    const int skg  = tid & 3;    // 0..3  (8 shorts each)

    for (int k0 = 0; k0 < K; k0 += 32) {
        __syncthreads();
        #pragma unroll
        for (int it = 0; it < 2; ++it) {
            int row = srow + it * 64;
            *(bf16x8*)(&As[row * 40 + skg * 8]) =
                *(const bf16x8*)(X + (size_t)(m0 + row) * K + k0 + skg * 8);
            *(bf16x8*)(&Bs[row * 40 + skg * 8]) =
                *(const bf16x8*)(W + (size_t)(n0 + row) * K + k0 + skg * 8);
        }
        __syncthreads();

        bf16x8 af[4], bf[4];
        #pragma unroll
        for (int mt = 0; mt < 4; ++mt)
            af[mt] = *(const bf16x8*)(&As[(wm * 64 + mt * 16 + l15) * 40 + quad * 8]);
        #pragma unroll
        for (int nt = 0; nt < 4; ++nt)
            bf[nt] = *(const bf16x8*)(&Bs[(wn * 64 + nt * 16 + l15) * 40 + quad * 8]);

        #pragma unroll
        for (int mt = 0; mt < 4; ++mt)
            #pragma unroll
            for (int nt = 0; nt < 4; ++nt)
                acc[mt][nt] = __builtin_amdgcn_mfma_f32_16x16x32_bf16(
                    af[mt], bf[nt], acc[mt][nt], 0, 0, 0);
    }

    float bv[4];
    #pragma unroll
    for (int nt = 0; nt < 4; ++nt)
        bv[nt] = bias[n0 + wn * 64 + nt * 16 + l15] * bscale;

    #pragma unroll
    for (int mt = 0; mt < 4; ++mt) {
        #pragma unroll
        for (int r = 0; r < 4; ++r) {
            int row = m0 + wm * 64 + mt * 16 + quad * 4 + r;   // C/D: row = quad*4+reg
            unsigned short* yp = Y + (size_t)row * 1024 + n0 + wn * 64;
            #pragma unroll
            for (int nt = 0; nt < 4; ++nt)
                yp[nt * 16 + l15] = f2b(acc[mt][nt][r] + bv[nt]);   // col = lane&15
        }
    }
}

// ---------------------------------------------------------------------------
// V transpose: Vb[b*2048+tok][h*64+d] -> Vt[((b*16+h)*64+d)][tok]
// 64x64 tiles via LDS. Grid (32 tok-tiles, 16 heads, 4 b).
// ---------------------------------------------------------------------------
__global__ __launch_bounds__(256) void transpose_v(
    const unsigned short* __restrict__ Vb, unsigned short* __restrict__ Vt)
{
    __shared__ unsigned short L[64 * 72];
    const int t0 = blockIdx.x * 64, h = blockIdx.y, b = blockIdx.z;
    const int rr = threadIdx.x >> 3;          // 0..31
    const int cc = (threadIdx.x & 7) * 8;     // 0..56

    #pragma unroll
    for (int p = 0; p < 2; ++p) {
        int r = rr + p * 32;   // tok within tile
        *(bf16x8*)(&L[r * 72 + cc]) =
            *(const bf16x8*)(Vb + (size_t)(b * 2048 + t0 + r) * 1024 + h * 64 + cc);
    }
    __syncthreads();
    #pragma unroll
    for (int p = 0; p < 2; ++p) {
        int d = rr + p * 32;
        bf16x8 v;
        #pragma unroll
        for (int j = 0; j < 8; ++j)
            v[j] = (short)L[(cc + j) * 72 + d];
        *(bf16x8*)(Vt + ((size_t)(b * 16 + h) * 64 + d) * 2048 + t0 + cc) = v;
    }
}

// ---------------------------------------------------------------------------
// Flash attention v2. Grid (qtile=32, head=16, batch=4), block 256 (4 waves),
// 64 queries/block (16/wave), 64-key tiles. Q pre-scaled by 1/8 (folded into
// Wq/bq). K staged [key][d]; V pre-transposed globally, staged [d][key].
// P round-trip through wave-private LDS (no barrier). Output fp32.
// ---------------------------------------------------------------------------
__global__ __launch_bounds__(256) void attn_kernel(
    const unsigned short* __restrict__ Q,
    const unsigned short* __restrict__ Kp,
    const unsigned short* __restrict__ Vt,
    float* __restrict__ Out)
{
    __shared__ unsigned short Ks[64 * 72];     // [key][d]
    __shared__ unsigned short Vs[64 * 72];     // [d][key]
    __shared__ unsigned short Ps[4][16 * 72];  // per-wave P [query][key]

    const int tid  = threadIdx.x;
    const int lane = tid & 63;
    const int w    = tid >> 6;
    const int l15  = lane & 15, quad = lane >> 4;
    const int b = blockIdx.z, h = blockIdx.y, qt = blockIdx.x;

    const unsigned short* qptr =
        Q + ((size_t)(b * LQ_ + qt * 64 + w * 16 + l15)) * 1024 + h * 64;
    bf16x8 qf[2];
    qf[0] = *(const bf16x8*)(qptr + 0  + quad * 8);
    qf[1] = *(const bf16x8*)(qptr + 32 + quad * 8);

    float mrow = -1e30f, lrow = 0.0f;
    f32x4 oacc[4] = {};

    const int sr = tid >> 3;          // 0..31
    const int sc = (tid & 7) * 8;     // 0..56
    const unsigned short* Kbase = Kp + (size_t)b * LK_ * 1024 + h * 64;
    const unsigned short* Vbase = Vt + ((size_t)(b * 16 + h) * 64) * 2048;

    for (int k0 = 0; k0 < LK_; k0 += 64) {
        __syncthreads();
        #pragma unroll
        for (int p = 0; p < 2; ++p) {
            int r = sr + p * 32;
            *(bf16x8*)(&Ks[r * 72 + sc]) =
                *(const bf16x8*)(Kbase + (size_t)(k0 + r) * 1024 + sc);
            *(bf16x8*)(&Vs[r * 72 + sc]) =
                *(const bf16x8*)(Vbase + (size_t)r * 2048 + k0 + sc);
        }
        __syncthreads();

        // S^T: A=K rows (m=key), B=Q (n=query). Lane holds keys 16t+quad*4+r, q=l15.
        f32x4 st[4];
        #pragma unroll
        for (int t = 0; t < 4; ++t) {
            f32x4 s = {};
            #pragma unroll
            for (int dblk = 0; dblk < 2; ++dblk) {
                bf16x8 kf = *(const bf16x8*)(&Ks[(t * 16 + l15) * 72 + dblk * 32 + quad * 8]);
                s = __builtin_amdgcn_mfma_f32_16x16x32_bf16(kf, qf[dblk], s, 0, 0, 0);
            }
            st[t] = s;
        }

        // online softmax (scale already folded into Q)
        float pm = -1e30f;
        #pragma unroll
        for (int t = 0; t < 4; ++t)
            #pragma unroll
            for (int r = 0; r < 4; ++r)
                pm = fmaxf(pm, st[t][r]);
        pm = fmaxf(pm, __shfl_xor(pm, 16, 64));
        pm = fmaxf(pm, __shfl_xor(pm, 32, 64));
        float mnew  = fmaxf(mrow, pm);
        float alpha = __expf(mrow - mnew);
        float psum  = 0.0f;
        #pragma unroll
        for (int t = 0; t < 4; ++t)
            #pragma unroll
            for (int r = 0; r < 4; ++r) {
                float p = __expf(st[t][r] - mnew);
                st[t][r] = p;
                psum += p;
            }
        psum += __shfl_xor(psum, 16, 64);
        psum += __shfl_xor(psum, 32, 64);
        lrow = lrow * alpha + psum;
        mrow = mnew;

        // P -> wave-private LDS [query][key] (bf16); in-wave DS order, no barrier
        unsigned short* pb = &Ps[w][0];
        #pragma unroll
        for (int t = 0; t < 4; ++t) {
            ushort4 pk;
            pk.x = f2b(st[t][0]); pk.y = f2b(st[t][1]);
            pk.z = f2b(st[t][2]); pk.w = f2b(st[t][3]);
            *(ushort4*)(&pb[l15 * 72 + t * 16 + quad * 4]) = pk;
        }
        bf16x8 pf0 = *(const bf16x8*)(&pb[l15 * 72 + 0  + quad * 8]);  // keys 0..31
        bf16x8 pf1 = *(const bf16x8*)(&pb[l15 * 72 + 32 + quad * 8]);  // keys 32..63

        float al[4];
        #pragma unroll
        for (int r = 0; r < 4; ++r) al[r] = __shfl(alpha, quad * 4 + r, 64);

        #pragma unroll
        for (int nt = 0; nt < 4; ++nt) {
            f32x4 o = oacc[nt];
            #pragma unroll
            for (int r = 0; r < 4; ++r) o[r] *= al[r];
            bf16x8 vf0 = *(const bf16x8*)(&Vs[(nt * 16 + l15) * 72 + 0  + quad * 8]);
            o = __builtin_amdgcn_mfma_f32_16x16x32_bf16(pf0, vf0, o, 0, 0, 0);
            bf16x8 vf1 = *(const bf16x8*)(&Vs[(nt * 16 + l15) * 72 + 32 + quad * 8]);
            o = __builtin_amdgcn_mfma_f32_16x16x32_bf16(pf1, vf1, o, 0, 0, 0);
            oacc[nt] = o;
        }
    }

    float invl = 1.0f / lrow;
    float il[4];
    #pragma unroll
    for (int r = 0; r < 4; ++r) il[r] = __shfl(invl, quad * 4 + r, 64);

    #pragma unroll
    for (int nt = 0; nt < 4; ++nt) {
        #pragma unroll
        for (int r = 0; r < 4; ++r) {
            size_t orow = (size_t)(b * LQ_ + qt * 64 + w * 16 + quad * 4 + r);
            Out[orow * 1024 + h * 64 + nt * 16 + l15] = oacc[nt][r] * il[r];
        }
    }
}

// ---------------------------------------------------------------------------
extern "C" void kernel_launch(void* const* d_in, const int* in_sizes, int n_in,
                              void* d_out, int out_size, void* d_ws, size_t ws_size,
                              hipStream_t stream) {
    const float* zt = (const float*)d_in[0];
    const float* ic = (const float*)d_in[1];
    const float* Wq = (const float*)d_in[2];
    const float* bq = (const float*)d_in[3];
    const float* Wk = (const float*)d_in[4];
    const float* bk = (const float*)d_in[5];
    const float* Wv = (const float*)d_in[6];
    const float* bv = (const float*)d_in[7];
    float* out = (float*)d_out;

    const size_t M8 = (size_t)8192 * 1024;   // 8M elems
    const size_t M1 = (size_t)1024 * 1024;   // 1M elems
    unsigned short* Qb  = (unsigned short*)d_ws;
    unsigned short* Kb  = Qb  + M8;
    unsigned short* Vb  = Kb  + M8;
    unsigned short* Xz  = Vb  + M8;          // reused as Vt after proj Q
    unsigned short* Xi  = Xz  + M8;
    unsigned short* Wqb = Xi  + M8;
    unsigned short* Wkb = Wqb + M1;
    unsigned short* Wvb = Wkb + M1;
    unsigned short* Vtb = Xz;                // alias: Xz dead after proj Q

    const float qscale = 0.125f;             // 1/sqrt(64), folded into Wq/bq

    cvt_bf16<<<4096, 256, 0, stream>>>(zt, Xz, (int)M8, 1.0f);
    cvt_bf16<<<4096, 256, 0, stream>>>(ic, Xi, (int)M8, 1.0f);
    cvt_bf16<<<512,  256, 0, stream>>>(Wq, Wqb, (int)M1, qscale);
    cvt_bf16<<<512,  256, 0, stream>>>(Wk, Wkb, (int)M1, 1.0f);
    cvt_bf16<<<512,  256, 0, stream>>>(Wv, Wvb, (int)M1, 1.0f);

    dim3 gproj(8, 64);                       // N/128, M/128
    proj_gemm<<<gproj, 256, 0, stream>>>(Xz, Wqb, bq, qscale, Qb);
    proj_gemm<<<gproj, 256, 0, stream>>>(Xi, Wkb, bk, 1.0f, Kb);
    proj_gemm<<<gproj, 256, 0, stream>>>(Xi, Wvb, bv, 1.0f, Vb);

    dim3 gtr(32, 16, 4);
    transpose_v<<<gtr, 256, 0, stream>>>(Vb, Vtb);

    dim3 gattn(32, 16, 4);                   // LQ/64, H, B
    attn_kernel<<<gattn, 256, 0, stream>>>(Qb, Kb, Vtb, out);
}